// Round 19
// baseline (4948.063 us; speedup 1.0000x reference)
//
#include <hip/hip_runtime.h>
#include <math.h>

// RNN: L=512, B=128, D=512, H=1024, fp32 in/out.
//   xproj = x @ Wx^T + bx -> d_out;  h_t = tanh(xp_t + h_{t-1} @ Wh^T) in place.
// Precision: split-bf16 (hi+lo), 3 MFMAs per product => ~fp32 accuracy.
// Round 19 = R17 + PER-WAVE RELEASE (delete the 2nd __syncthreads):
//  - R18 null: burst widening not the residual. The untouched term is the
//    release barrier: R13 forces the WHOLE WG to resync before tid0 publishes
//    one flag. Now each wave drains its OWN 2 h-stores and publishes its OWN
//    flag -> consumers unblock ~0.3-0.5us earlier, one barrier/step total.
//  - Flags [4][64][8]; consumer wave q polls the 64 producer-WAVE flags
//    covering cols [q*128,+128) (one/lane, contiguous).
//  - LDS partials parity-double-buffered (34.8KB): the single per-step
//    barrier bounds sibling skew; safety argument preserved (a wave writing
//    part[(t+2)&1] passed sync(t+1) => siblings finished reduce(t); h_t
//    stores follow sync(t) whose 8 gates cover ALL 512 group-wave flags >= t
//    => plane-(t-2) reads complete before overwrite).

#define L_SEQ 512
#define B_SZ  128
#define D_SZ  512
#define H_SZ  1024
#define BH    (B_SZ * H_SZ)   // 131072

typedef __bf16 bf16x8 __attribute__((ext_vector_type(8)));
typedef float  f32x4  __attribute__((ext_vector_type(4)));
typedef unsigned int uint;
typedef unsigned short ushort;

union V8 { bf16x8 b; ushort u[8]; uint w[4]; };

__device__ __forceinline__ ushort f2bf(float f) {
  uint u = __float_as_uint(f);
  u += 0x7FFFu + ((u >> 16) & 1u);   // round-to-nearest-even
  return (ushort)(u >> 16);
}
__device__ __forceinline__ float bf2f(ushort s) {
  return __uint_as_float(((uint)s) << 16);
}

// tanh(x) = 1 - 2/(e^{2x}+1); v_exp_f32(2^x) + v_rcp_f32. Saturates right.
__device__ __forceinline__ float fast_tanh(float x) {
  float e;
  asm("v_exp_f32 %0, %1" : "=v"(e) : "v"(x * 2.885390081777927f));
  float r;
  asm("v_rcp_f32 %0, %1" : "=v"(r) : "v"(e + 1.0f));
  return 1.0f - 2.0f * r;
}

// Agent-scope (sc0 sc1): bypass L1+L2, coherent at the L3 point. PROVEN (R8).
__device__ __forceinline__ void ldg16_sc(bf16x8& d, const ushort* p) {
  asm volatile("global_load_dwordx4 %0, %1, off sc0 sc1"
               : "=v"(d) : "v"(p) : "memory");
}
__device__ __forceinline__ void stg2_sc(ushort* p, uint v) {
  asm volatile("global_store_short %0, %1, off sc0 sc1"
               :: "v"(p), "v"(v) : "memory");
}
__device__ __forceinline__ void stg4_sc(uint* p, uint v) {
  asm volatile("global_store_dword %0, %1, off sc0 sc1"
               :: "v"(p), "v"(v) : "memory");
}

// ---- d_ws layout (ushort elements unless noted) ----
#define WS_WHH 0            // [1024][1024]
#define WS_WHL 1048576      // [1024][1024]
#define WS_WXH 2097152      // [1024][512]
#define WS_WXL 2621440      // [1024][512]
#define WS_HB  3145728      // [2 parity][2 hi/lo][BH] ushort
#define WS_CNT 3670016      // wflags: [4 mb][64 nb][8 wave] u32 (2048 words)

// Split fp32 weights into bf16 hi + bf16 lo(residual); zero wave flags.
__global__ void split_kernel(const float* __restrict__ Wh,
                             const float* __restrict__ Wx,
                             ushort* __restrict__ ws,
                             uint* __restrict__ flags) {
  if (blockIdx.x < 8) {
    int i = blockIdx.x * 256 + threadIdx.x;
    flags[i] = 0u;
  }
  const int total = 1048576 + 524288;
  for (int i = blockIdx.x * blockDim.x + threadIdx.x; i < total;
       i += gridDim.x * blockDim.x) {
    const float* src; ushort *dh, *dl; int j;
    if (i < 1048576) { src = Wh; dh = ws + WS_WHH; dl = ws + WS_WHL; j = i; }
    else             { src = Wx; dh = ws + WS_WXH; dl = ws + WS_WXL; j = i - 1048576; }
    float v = src[j];
    ushort h = f2bf(v);
    dh[j] = h;
    dl[j] = f2bf(v - bf2f(h));
  }
}

// xproj v2 (R17): BM=128, BN=256; 2048 blocks x 512 thr; 48 MFMAs/chunk.
__global__ __launch_bounds__(512) void xproj_kernel(
    const float* __restrict__ x,             // [65536][512]
    const ushort* __restrict__ wxh,          // [1024][512]
    const ushort* __restrict__ wxl,
    const float* __restrict__ bx,            // [1024]
    float* __restrict__ out)                 // [65536][1024]
{
  const int bid = blockIdx.x;
  const int bn = bid & 3;
  const int bm = bid >> 2;
  const int tid = threadIdx.x;
  const int w = tid >> 6, l = tid & 63;
  const int wm = w & 1, wn = w >> 1;
  const int lr = l & 15, lk = (l >> 4) * 8;
  const int mbase = bm * 128 + wm * 64;
  const int nbase = bn * 256 + wn * 64;

  f32x4 acc[4][4] = {};

  for (int k0 = 0; k0 < 512; k0 += 32) {
    bf16x8 ah[4], al[4], bh[4], bl[4];
#pragma unroll
    for (int i = 0; i < 4; ++i) {
      const float* ap = x + (size_t)(mbase + i * 16 + lr) * 512 + k0 + lk;
      float4 v0 = *reinterpret_cast<const float4*>(ap);
      float4 v1 = *reinterpret_cast<const float4*>(ap + 4);
      float vv[8] = {v0.x, v0.y, v0.z, v0.w, v1.x, v1.y, v1.z, v1.w};
      V8 hh, ll;
#pragma unroll
      for (int e = 0; e < 8; ++e) {
        ushort hb = f2bf(vv[e]);
        hh.u[e] = hb;
        ll.u[e] = f2bf(vv[e] - bf2f(hb));
      }
      ah[i] = hh.b; al[i] = ll.b;
    }
#pragma unroll
    for (int j = 0; j < 4; ++j) {
      size_t boff = (size_t)(nbase + j * 16 + lr) * 512 + k0 + lk;
      bh[j] = *reinterpret_cast<const bf16x8*>(wxh + boff);
      bl[j] = *reinterpret_cast<const bf16x8*>(wxl + boff);
    }
#pragma unroll
    for (int i = 0; i < 4; ++i)
#pragma unroll
      for (int j = 0; j < 4; ++j) {
        acc[i][j] = __builtin_amdgcn_mfma_f32_16x16x32_bf16(ah[i], bh[j], acc[i][j], 0, 0, 0);
        acc[i][j] = __builtin_amdgcn_mfma_f32_16x16x32_bf16(ah[i], bl[j], acc[i][j], 0, 0, 0);
        acc[i][j] = __builtin_amdgcn_mfma_f32_16x16x32_bf16(al[i], bh[j], acc[i][j], 0, 0, 0);
      }
  }

#pragma unroll
  for (int j = 0; j < 4; ++j) {
    int n = nbase + j * 16 + lr;
    float bxv = bx[n];
#pragma unroll
    for (int i = 0; i < 4; ++i)
#pragma unroll
      for (int r = 0; r < 4; ++r) {
        int m = mbase + i * 16 + (l >> 4) * 4 + r;
        out[(size_t)m * 1024 + n] = acc[i][j][r] + bxv;
      }
  }
}

// Persistent recurrence — R13 protocol with per-wave release.
// 256 WGs x 512 threads. WG (mb,nb): rows [mb*32,+32) x cols [nb*16,+16).
// Wave q: K-slice [q*128,+128); Wh frags in registers throughout.
// Gate: wave q at step t polls the 64 producer-WAVE flags (WGs nb' in
// [8q,8q+8) x waves 0..7) for >= t. Release: wave drains its OWN h-stores
// then lane0 publishes its OWN flag — no release barrier.
__global__ __launch_bounds__(512, 2) void rnn_persistent(
    const ushort* __restrict__ whh,  // [1024][1024]
    const ushort* __restrict__ whl,
    ushort* __restrict__ hb,         // [2 parity][2 hi/lo][BH]
    float* __restrict__ out,         // [512][BH] (xproj in, h out)
    uint* __restrict__ flags)        // [4][64][8]
{
  __shared__ float part[2][8][544];          // parity-dbuf, 34816 B
  const int wg = blockIdx.x;                 // 0..255
  const int xc = wg & 7, yy = wg >> 3;
  const int mb = xc & 3;
  const int nb = ((xc >> 2) << 5) + yy;      // 0..63
  const int tid = threadIdx.x;
  const int q = tid >> 6;                    // wave / k-slice 0..7
  const int l = tid & 63;
  const int lr = l & 15, lk = (l >> 4) * 8;
  const int kbase = q * 128 + lk;
  const int row0 = (l >> 4) * 4;

  const ushort* bph = whh + (size_t)(nb * 16 + lr) * 1024 + kbase;
  const ushort* bpl = whl + (size_t)(nb * 16 + lr) * 1024 + kbase;
  bf16x8 vBh[4], vBl[4];
#pragma unroll
  for (int kb = 0; kb < 4; ++kb) {
    vBh[kb] = *reinterpret_cast<const bf16x8*>(bph + kb * 32);
    vBl[kb] = *reinterpret_cast<const bf16x8*>(bpl + kb * 32);
  }

  const size_t aoff = (size_t)(mb * 32 + lr) * 1024 + kbase;
  const ushort* planeA0 = hb + aoff;            // parity 0 hi
  const ushort* planeA1 = hb + 2 * BH + aoff;   // parity 1 hi

  const int em = tid >> 4, en = tid & 15;
  const size_t eidx = (size_t)(mb * 32 + em) * 1024 + nb * 16 + en;

  // Gate: 64 producer-wave flags, one per lane (contiguous block).
  const uint* gate_ptr = flags + (mb << 9) + (q << 6) + l;
  uint* my_flag = flags + (mb << 9) + (nb << 3) + q;

  for (int t = 0; t < L_SEQ; ++t) {
    float* xpt = out + (size_t)t * BH;
    const float xpv = xpt[eidx];             // prefetch; overlaps gate wait
    float hval;

    if (t > 0) {
      const uint tgt = (uint)t;
      for (uint spin = 0; spin < (1u << 20); ++spin) {
        uint f;
        asm volatile("global_load_dword %0, %1, off sc0 sc1\n\t"
                     "s_waitcnt vmcnt(0)"
                     : "=v"(f) : "v"(gate_ptr) : "memory");
        if (__all((int)(f >= tgt))) break;
        __builtin_amdgcn_s_sleep(1);
      }
      __builtin_amdgcn_sched_barrier(0);     // nothing drifts above the gate

      const ushort* ah = ((t - 1) & 1) ? planeA1 : planeA0;
      const ushort* al = ah + BH;
      bf16x8 vA0h[4], vA0l[4], vA1h[4], vA1l[4];
#pragma unroll
      for (int kb = 0; kb < 4; ++kb) {
        const int ko = kb * 32;
        ldg16_sc(vA0h[kb], ah + ko);
        ldg16_sc(vA0l[kb], al + ko);
        ldg16_sc(vA1h[kb], ah + 16 * 1024 + ko);
        ldg16_sc(vA1l[kb], al + 16 * 1024 + ko);
      }
      asm volatile("s_waitcnt vmcnt(0)" ::: "memory");
      __builtin_amdgcn_sched_barrier(0);     // rule #18: no consumer hoists

      f32x4 acc0 = {0.f, 0.f, 0.f, 0.f};
      f32x4 acc1 = {0.f, 0.f, 0.f, 0.f};
#pragma unroll
      for (int kb = 0; kb < 4; ++kb) {
        acc0 = __builtin_amdgcn_mfma_f32_16x16x32_bf16(vA0h[kb], vBh[kb], acc0, 0, 0, 0);
        acc1 = __builtin_amdgcn_mfma_f32_16x16x32_bf16(vA1h[kb], vBh[kb], acc1, 0, 0, 0);
        acc0 = __builtin_amdgcn_mfma_f32_16x16x32_bf16(vA0h[kb], vBl[kb], acc0, 0, 0, 0);
        acc1 = __builtin_amdgcn_mfma_f32_16x16x32_bf16(vA1h[kb], vBl[kb], acc1, 0, 0, 0);
        acc0 = __builtin_amdgcn_mfma_f32_16x16x32_bf16(vA0l[kb], vBh[kb], acc0, 0, 0, 0);
        acc1 = __builtin_amdgcn_mfma_f32_16x16x32_bf16(vA1l[kb], vBh[kb], acc1, 0, 0, 0);
      }

      // Partials -> parity-dbuf LDS. col = lane&15, row = (lane>>4)*4 + r.
      float* pp = &part[t & 1][q][0];
#pragma unroll
      for (int r = 0; r < 4; ++r) {
        pp[(row0 + r) * 17 + lr]      = acc0[r];
        pp[(16 + row0 + r) * 17 + lr] = acc1[r];
      }
      __syncthreads();                       // the ONE barrier per step

      float s = 0.f;
#pragma unroll
      for (int qq = 0; qq < 8; ++qq) s += part[t & 1][qq][em * 17 + en];
      hval = fast_tanh(s + xpv);
    } else {
      hval = fast_tanh(xpv);
    }

    // Per-wave release: own h stores -> own drain -> own flag. No barrier.
    ushort hhi = f2bf(hval);
    ushort hlo = f2bf(hval - bf2f(hhi));
    ushort* hcur = hb + (size_t)((t & 1) * 2) * BH;
    stg2_sc(hcur + eidx, (uint)hhi);
    stg2_sc(hcur + BH + eidx, (uint)hlo);
    asm volatile("s_waitcnt vmcnt(0)" ::: "memory");
    if (l == 0) stg4_sc(my_flag, (uint)(t + 1));

    // Off the critical path: fp32 h into d_out (never read by consumers).
    xpt[eidx] = hval;
  }
}

extern "C" void kernel_launch(void* const* d_in, const int* in_sizes, int n_in,
                              void* d_out, int out_size, void* d_ws, size_t ws_size,
                              hipStream_t stream) {
  const float* x  = (const float*)d_in[0];   // [512][128][512]
  const float* Wx = (const float*)d_in[1];   // [1024][512]
  const float* bx = (const float*)d_in[2];   // [1024]
  const float* Wh = (const float*)d_in[3];   // [1024][1024]
  float* out = (float*)d_out;                // [512][128][1024]
  ushort* ws = (ushort*)d_ws;

  ushort* whh = ws + WS_WHH;
  ushort* whl = ws + WS_WHL;
  ushort* wxh = ws + WS_WXH;
  ushort* wxl = ws + WS_WXL;
  ushort* hb  = ws + WS_HB;                  // [2][2][BH]
  uint* flags = (uint*)(ws + WS_CNT);        // [4][64][8]

  split_kernel<<<dim3(2048), dim3(256), 0, stream>>>(Wh, Wx, ws, flags);
  xproj_kernel<<<dim3(2048), dim3(512), 0, stream>>>(x, wxh, wxl, bx, out);
  rnn_persistent<<<dim3(256), dim3(512), 0, stream>>>(whh, whl, hb, out, flags);
}

// Round 20
// 3473.049 us; speedup vs baseline: 1.4247x; 1.4247x over previous
//
#include <hip/hip_runtime.h>
#include <math.h>

// RNN: L=512, B=128, D=512, H=1024, fp32 in/out.
//   xproj = x @ Wx^T + bx -> d_out;  h_t = tanh(xp_t + h_{t-1} @ Wh^T) in place.
// Precision: split-bf16 (hi+lo), 3 MFMAs per product => ~fp32 accuracy.
// Round 20 = CHAMPION RESTORE (R17 verbatim; R19's per-wave release regressed
// 3,010->4,430us via 8x flag traffic + slowest-of-64 waits).
// Final structure & why (19-round ledger):
//  - split: fp32 weights -> bf16 hi+lo planes (~25us).
//  - xproj v2: BM=128 BN=256, 48 MFMAs/chunk, x re-read 4x (~425us).
//  - recurrence: persistent 256 WGs x 8 waves; WG (mb,nb) owns a 32x16 tile
//    for all 512 steps; Wh frags register-resident; K-split-8 + LDS reduce;
//    h exchanged via agent-scope (sc0sc1) bypass ops; release = stores ->
//    vmcnt(0) drain -> WG barrier -> per-WG flag; gate = 8 producer flags.
//    5.9us/step = ~3 L3 hops + compute; survived 8 restructuring attempts
//    (fences/atomics/packing/scopes/tags/dual-chain/fusion/per-wave flags)
//    -> demonstrated local optimum for this cross-CU dependency chain.

#define L_SEQ 512
#define B_SZ  128
#define D_SZ  512
#define H_SZ  1024
#define BH    (B_SZ * H_SZ)   // 131072

typedef __bf16 bf16x8 __attribute__((ext_vector_type(8)));
typedef float  f32x4  __attribute__((ext_vector_type(4)));
typedef unsigned int uint;
typedef unsigned short ushort;

union V8 { bf16x8 b; ushort u[8]; uint w[4]; };

__device__ __forceinline__ ushort f2bf(float f) {
  uint u = __float_as_uint(f);
  u += 0x7FFFu + ((u >> 16) & 1u);   // round-to-nearest-even
  return (ushort)(u >> 16);
}
__device__ __forceinline__ float bf2f(ushort s) {
  return __uint_as_float(((uint)s) << 16);
}

// tanh(x) = 1 - 2/(e^{2x}+1); v_exp_f32(2^x) + v_rcp_f32. Saturates right.
__device__ __forceinline__ float fast_tanh(float x) {
  float e;
  asm("v_exp_f32 %0, %1" : "=v"(e) : "v"(x * 2.885390081777927f));
  float r;
  asm("v_rcp_f32 %0, %1" : "=v"(r) : "v"(e + 1.0f));
  return 1.0f - 2.0f * r;
}

// Agent-scope (sc0 sc1): bypass L1+L2, coherent at the L3 point. PROVEN (R8).
__device__ __forceinline__ void ldg16_sc(bf16x8& d, const ushort* p) {
  asm volatile("global_load_dwordx4 %0, %1, off sc0 sc1"
               : "=v"(d) : "v"(p) : "memory");
}
__device__ __forceinline__ void stg2_sc(ushort* p, uint v) {
  asm volatile("global_store_short %0, %1, off sc0 sc1"
               :: "v"(p), "v"(v) : "memory");
}
__device__ __forceinline__ void stg4_sc(uint* p, uint v) {
  asm volatile("global_store_dword %0, %1, off sc0 sc1"
               :: "v"(p), "v"(v) : "memory");
}

// ---- d_ws layout (ushort elements unless noted) ----
#define WS_WHH 0            // [1024][1024]
#define WS_WHL 1048576      // [1024][1024]
#define WS_WXH 2097152      // [1024][512]
#define WS_WXL 2621440      // [1024][512]
#define WS_HB  3145728      // [2 parity][2 hi/lo][BH] ushort
#define WS_CNT 3670016      // flags: [4 mb][64 nb] u32 (zeroed per launch)

// Split fp32 weights into bf16 hi + bf16 lo(residual); zero flags.
__global__ void split_kernel(const float* __restrict__ Wh,
                             const float* __restrict__ Wx,
                             ushort* __restrict__ ws,
                             uint* __restrict__ flags) {
  if (blockIdx.x == 0) {
    for (int i = threadIdx.x; i < 512; i += 256) flags[i] = 0u;
  }
  const int total = 1048576 + 524288;
  for (int i = blockIdx.x * blockDim.x + threadIdx.x; i < total;
       i += gridDim.x * blockDim.x) {
    const float* src; ushort *dh, *dl; int j;
    if (i < 1048576) { src = Wh; dh = ws + WS_WHH; dl = ws + WS_WHL; j = i; }
    else             { src = Wx; dh = ws + WS_WXH; dl = ws + WS_WXL; j = i - 1048576; }
    float v = src[j];
    ushort h = f2bf(v);
    dh[j] = h;
    dl[j] = f2bf(v - bf2f(h));
  }
}

// xproj v2: out[m][n] = sum_d x[m][d]*Wx[n][d] + bx[n].
// BM=128, BN=256; 2048 blocks x 512 thr (8 waves, 2M x 4N, wave tile 64x64).
__global__ __launch_bounds__(512) void xproj_kernel(
    const float* __restrict__ x,             // [65536][512]
    const ushort* __restrict__ wxh,          // [1024][512]
    const ushort* __restrict__ wxl,
    const float* __restrict__ bx,            // [1024]
    float* __restrict__ out)                 // [65536][1024]
{
  const int bid = blockIdx.x;
  const int bn = bid & 3;        // 4 N-blocks of 256 (fastest: share x rows)
  const int bm = bid >> 2;       // 512 M-blocks of 128
  const int tid = threadIdx.x;
  const int w = tid >> 6, l = tid & 63;
  const int wm = w & 1, wn = w >> 1;         // 2(M) x 4(N) waves
  const int lr = l & 15, lk = (l >> 4) * 8;
  const int mbase = bm * 128 + wm * 64;
  const int nbase = bn * 256 + wn * 64;

  f32x4 acc[4][4] = {};

  for (int k0 = 0; k0 < 512; k0 += 32) {
    bf16x8 ah[4], al[4], bh[4], bl[4];
#pragma unroll
    for (int i = 0; i < 4; ++i) {
      const float* ap = x + (size_t)(mbase + i * 16 + lr) * 512 + k0 + lk;
      float4 v0 = *reinterpret_cast<const float4*>(ap);
      float4 v1 = *reinterpret_cast<const float4*>(ap + 4);
      float vv[8] = {v0.x, v0.y, v0.z, v0.w, v1.x, v1.y, v1.z, v1.w};
      V8 hh, ll;
#pragma unroll
      for (int e = 0; e < 8; ++e) {
        ushort hb = f2bf(vv[e]);
        hh.u[e] = hb;
        ll.u[e] = f2bf(vv[e] - bf2f(hb));
      }
      ah[i] = hh.b; al[i] = ll.b;
    }
#pragma unroll
    for (int j = 0; j < 4; ++j) {
      size_t boff = (size_t)(nbase + j * 16 + lr) * 512 + k0 + lk;
      bh[j] = *reinterpret_cast<const bf16x8*>(wxh + boff);
      bl[j] = *reinterpret_cast<const bf16x8*>(wxl + boff);
    }
#pragma unroll
    for (int i = 0; i < 4; ++i)
#pragma unroll
      for (int j = 0; j < 4; ++j) {
        acc[i][j] = __builtin_amdgcn_mfma_f32_16x16x32_bf16(ah[i], bh[j], acc[i][j], 0, 0, 0);
        acc[i][j] = __builtin_amdgcn_mfma_f32_16x16x32_bf16(ah[i], bl[j], acc[i][j], 0, 0, 0);
        acc[i][j] = __builtin_amdgcn_mfma_f32_16x16x32_bf16(al[i], bh[j], acc[i][j], 0, 0, 0);
      }
  }

  // Epilogue. C/D layout: col = lane&15, row = (lane>>4)*4 + r.
#pragma unroll
  for (int j = 0; j < 4; ++j) {
    int n = nbase + j * 16 + lr;
    float bxv = bx[n];
#pragma unroll
    for (int i = 0; i < 4; ++i)
#pragma unroll
      for (int r = 0; r < 4; ++r) {
        int m = mbase + i * 16 + (l >> 4) * 4 + r;
        out[(size_t)m * 1024 + n] = acc[i][j][r] + bxv;
      }
  }
}

// Persistent recurrence — champion protocol (R13/R17).
// 256 WGs x 512 threads. WG (mb,nb): rows [mb*32,+32) x cols [nb*16,+16).
// Wave q owns K-slice [q*128,+128); Wh frags in registers throughout.
// Gate: wave q at step t waits flag[mb][8q+p] >= t for p=0..7. Flags publish
// after h-store drain (vmcnt(0)+__syncthreads) -> flag seen => h visible.
__global__ __launch_bounds__(512, 2) void rnn_persistent(
    const ushort* __restrict__ whh,  // [1024][1024]
    const ushort* __restrict__ whl,
    ushort* __restrict__ hb,         // [2 parity][2 hi/lo][BH]
    float* __restrict__ out,         // [512][BH] (xproj in, h out)
    uint* __restrict__ flags)        // [4][64]
{
  __shared__ float lds[8 * 32 * 17];         // 17408 B, stride-17 pad
  const int wg = blockIdx.x;                 // 0..255
  const int xc = wg & 7, yy = wg >> 3;
  const int mb = xc & 3;
  const int nb = ((xc >> 2) << 5) + yy;      // 0..63
  const int tid = threadIdx.x;
  const int q = tid >> 6;                    // k-slice 0..7
  const int l = tid & 63;
  const int lr = l & 15, lk = (l >> 4) * 8;
  const int kbase = q * 128 + lk;
  const int row0 = (l >> 4) * 4;

  const ushort* bph = whh + (size_t)(nb * 16 + lr) * 1024 + kbase;
  const ushort* bpl = whl + (size_t)(nb * 16 + lr) * 1024 + kbase;
  bf16x8 vBh[4], vBl[4];
#pragma unroll
  for (int kb = 0; kb < 4; ++kb) {
    vBh[kb] = *reinterpret_cast<const bf16x8*>(bph + kb * 32);
    vBl[kb] = *reinterpret_cast<const bf16x8*>(bpl + kb * 32);
  }

  const size_t aoff = (size_t)(mb * 32 + lr) * 1024 + kbase;
  const ushort* planeA0 = hb + aoff;            // parity 0 hi
  const ushort* planeA1 = hb + 2 * BH + aoff;   // parity 1 hi

  const int em = tid >> 4, en = tid & 15;
  const size_t eidx = (size_t)(mb * 32 + em) * 1024 + nb * 16 + en;

  const uint* gate_ptr = flags + (mb << 6) + (q << 3) + (l & 7);
  uint* my_flag = flags + (mb << 6) + nb;

  for (int t = 0; t < L_SEQ; ++t) {
    float* xpt = out + (size_t)t * BH;
    const float xpv = xpt[eidx];             // prefetch; overlaps gate wait
    float hval;

    if (t > 0) {
      const uint tgt = (uint)t;
      for (uint spin = 0; spin < (1u << 20); ++spin) {
        uint f;
        asm volatile("global_load_dword %0, %1, off sc0 sc1\n\t"
                     "s_waitcnt vmcnt(0)"
                     : "=v"(f) : "v"(gate_ptr) : "memory");
        if (__all((int)(f >= tgt))) break;
        __builtin_amdgcn_s_sleep(1);
      }
      __builtin_amdgcn_sched_barrier(0);     // nothing drifts above the gate

      const ushort* ah = ((t - 1) & 1) ? planeA1 : planeA0;
      const ushort* al = ah + BH;
      bf16x8 vA0h[4], vA0l[4], vA1h[4], vA1l[4];
#pragma unroll
      for (int kb = 0; kb < 4; ++kb) {
        const int ko = kb * 32;
        ldg16_sc(vA0h[kb], ah + ko);
        ldg16_sc(vA0l[kb], al + ko);
        ldg16_sc(vA1h[kb], ah + 16 * 1024 + ko);
        ldg16_sc(vA1l[kb], al + 16 * 1024 + ko);
      }
      asm volatile("s_waitcnt vmcnt(0)" ::: "memory");
      __builtin_amdgcn_sched_barrier(0);     // rule #18: no consumer hoists

      f32x4 acc0 = {0.f, 0.f, 0.f, 0.f};
      f32x4 acc1 = {0.f, 0.f, 0.f, 0.f};
#pragma unroll
      for (int kb = 0; kb < 4; ++kb) {
        acc0 = __builtin_amdgcn_mfma_f32_16x16x32_bf16(vA0h[kb], vBh[kb], acc0, 0, 0, 0);
        acc1 = __builtin_amdgcn_mfma_f32_16x16x32_bf16(vA1h[kb], vBh[kb], acc1, 0, 0, 0);
        acc0 = __builtin_amdgcn_mfma_f32_16x16x32_bf16(vA0h[kb], vBl[kb], acc0, 0, 0, 0);
        acc1 = __builtin_amdgcn_mfma_f32_16x16x32_bf16(vA1h[kb], vBl[kb], acc1, 0, 0, 0);
        acc0 = __builtin_amdgcn_mfma_f32_16x16x32_bf16(vA0l[kb], vBh[kb], acc0, 0, 0, 0);
        acc1 = __builtin_amdgcn_mfma_f32_16x16x32_bf16(vA1l[kb], vBh[kb], acc1, 0, 0, 0);
      }

      // Partials -> LDS. C/D layout: col = lane&15, row = (lane>>4)*4 + r.
#pragma unroll
      for (int r = 0; r < 4; ++r) {
        lds[q * 544 + (row0 + r) * 17 + lr]      = acc0[r];
        lds[q * 544 + (16 + row0 + r) * 17 + lr] = acc1[r];
      }
      __syncthreads();   // all waves' partials in LDS (=> all gates passed)

      float s = 0.f;
#pragma unroll
      for (int qq = 0; qq < 8; ++qq) s += lds[qq * 544 + em * 17 + en];
      hval = fast_tanh(s + xpv);
    } else {
      hval = fast_tanh(xpv);
    }

    // Release path: bf16 hi/lo stores -> drain -> WG sync -> flag.
    ushort hhi = f2bf(hval);
    ushort hlo = f2bf(hval - bf2f(hhi));
    ushort* hcur = hb + (size_t)((t & 1) * 2) * BH;
    stg2_sc(hcur + eidx, (uint)hhi);
    stg2_sc(hcur + BH + eidx, (uint)hlo);
    asm volatile("s_waitcnt vmcnt(0)" ::: "memory");
    __syncthreads();   // also protects LDS against next step's overwrite
    if (tid == 0) stg4_sc(my_flag, (uint)(t + 1));

    // Off the critical path: fp32 h into d_out (never read by consumers).
    xpt[eidx] = hval;
  }
}

extern "C" void kernel_launch(void* const* d_in, const int* in_sizes, int n_in,
                              void* d_out, int out_size, void* d_ws, size_t ws_size,
                              hipStream_t stream) {
  const float* x  = (const float*)d_in[0];   // [512][128][512]
  const float* Wx = (const float*)d_in[1];   // [1024][512]
  const float* bx = (const float*)d_in[2];   // [1024]
  const float* Wh = (const float*)d_in[3];   // [1024][1024]
  float* out = (float*)d_out;                // [512][128][1024]
  ushort* ws = (ushort*)d_ws;

  ushort* whh = ws + WS_WHH;
  ushort* whl = ws + WS_WHL;
  ushort* wxh = ws + WS_WXH;
  ushort* wxl = ws + WS_WXL;
  ushort* hb  = ws + WS_HB;                  // [2][2][BH]
  uint* flags = (uint*)(ws + WS_CNT);

  split_kernel<<<dim3(2048), dim3(256), 0, stream>>>(Wh, Wx, ws, flags);
  xproj_kernel<<<dim3(2048), dim3(512), 0, stream>>>(x, wxh, wxl, bx, out);
  rnn_persistent<<<dim3(256), dim3(512), 0, stream>>>(whh, whl, hb, out, flags);
}